// Round 5
// baseline (8150.790 us; speedup 1.0000x reference)
//
#include <hip/hip_runtime.h>

#define N_NODES 100000
#define N_EDGES 1600000
#define F 64
#define NCHUNK 196           // ceil(N_NODES/512)

static_assert(N_NODES % 8 == 0, "node groups exact");
static_assert(N_EDGES % 16 == 0, "edge groups exact");

using short8 = __attribute__((ext_vector_type(8))) short;  // 8 bf16 (4 VGPRs)
using f32x4  = __attribute__((ext_vector_type(4))) float;
using u32x4  = __attribute__((ext_vector_type(4))) unsigned;

#define WSTRU 68  // uint stride for packed weight rows (16B multiple, odd/4)
#define MSTR  68  // uint stride for packed m buffer rows
#define NSTR  68  // float stride for node-kernel transposed weights

__device__ __forceinline__ float silu_f(float v) {
    return v / (1.0f + __expf(-v));
}
__device__ __forceinline__ short f2bf(float f) {          // f32 -> bf16 RNE
    unsigned u = __float_as_uint(f);
    unsigned r = (u + 0x7fffu + ((u >> 16) & 1u)) >> 16;
    return (short)r;
}
__device__ __forceinline__ float bf2f(short s) {
    return __uint_as_float(((unsigned)(unsigned short)s) << 16);
}
__device__ __forceinline__ float bcast(float v, int l) {  // v_readlane
    return __int_as_float(__builtin_amdgcn_readlane(__float_as_int(v), l));
}
// unpack 8 packed (hi<<16|lo) uints into hi/lo short8 via v_perm_b32
__device__ __forceinline__ void unpack8(const u32x4 u0, const u32x4 u1,
                                        short8* hi, short8* lo) {
    union { unsigned d[4]; short8 s; } H, L;
    H.d[0] = __builtin_amdgcn_perm(u0[1], u0[0], 0x07060302u);
    H.d[1] = __builtin_amdgcn_perm(u0[3], u0[2], 0x07060302u);
    H.d[2] = __builtin_amdgcn_perm(u1[1], u1[0], 0x07060302u);
    H.d[3] = __builtin_amdgcn_perm(u1[3], u1[2], 0x07060302u);
    L.d[0] = __builtin_amdgcn_perm(u0[1], u0[0], 0x05040100u);
    L.d[1] = __builtin_amdgcn_perm(u0[3], u0[2], 0x05040100u);
    L.d[2] = __builtin_amdgcn_perm(u1[1], u1[0], 0x05040100u);
    L.d[3] = __builtin_amdgcn_perm(u1[3], u1[2], 0x05040100u);
    *hi = H.s; *lo = L.s;
}

// ---------------- counting sort of edges by dst ----------------
__global__ __launch_bounds__(256) void sort_zero(unsigned* __restrict__ counts) {
    const int i = blockIdx.x * 256 + threadIdx.x;
    const int stride = gridDim.x * 256;
    for (int j = i; j < N_NODES; j += stride) counts[j] = 0u;
}
__global__ __launch_bounds__(256) void sort_hist(const int* __restrict__ dst,
                                                 unsigned* __restrict__ counts) {
    const int i = blockIdx.x * 256 + threadIdx.x;
    const int stride = gridDim.x * 256;
    for (int e = i; e < N_EDGES; e += stride)
        atomicAdd(&counts[dst[e]], 1u);
}
__global__ __launch_bounds__(512) void sort_chunk_sums(const unsigned* __restrict__ counts,
                                                       unsigned* __restrict__ partial) {
    __shared__ unsigned red[512];
    const int t = threadIdx.x;
    const int i = blockIdx.x * 512 + t;
    red[t] = (i < N_NODES) ? counts[i] : 0u;
    __syncthreads();
    for (int off = 256; off >= 1; off >>= 1) {
        if (t < off) red[t] += red[t + off];
        __syncthreads();
    }
    if (t == 0) partial[blockIdx.x] = red[0];
}
__global__ __launch_bounds__(256) void sort_scan_partials(unsigned* __restrict__ partial) {
    __shared__ unsigned tmp[256];
    const int t = threadIdx.x;
    const unsigned v = (t < NCHUNK) ? partial[t] : 0u;
    tmp[t] = v;
    __syncthreads();
    for (int off = 1; off < 256; off <<= 1) {
        const unsigned a = (t >= off) ? tmp[t - off] : 0u;
        __syncthreads();
        tmp[t] += a;
        __syncthreads();
    }
    if (t < NCHUNK) partial[t] = tmp[t] - v;   // exclusive
}
__global__ __launch_bounds__(512) void sort_scan_chunks(unsigned* __restrict__ counts,
                                                        const unsigned* __restrict__ partial) {
    __shared__ unsigned tmp[512];
    const int t = threadIdx.x;
    const int i = blockIdx.x * 512 + t;
    const unsigned v = (i < N_NODES) ? counts[i] : 0u;
    tmp[t] = v;
    __syncthreads();
    for (int off = 1; off < 512; off <<= 1) {
        const unsigned a = (t >= off) ? tmp[t - off] : 0u;
        __syncthreads();
        tmp[t] += a;
        __syncthreads();
    }
    if (i < N_NODES) counts[i] = tmp[t] - v + partial[blockIdx.x];  // exclusive offsets
}
__global__ __launch_bounds__(256) void sort_scatter(const int* __restrict__ src,
                                                    const int* __restrict__ dst,
                                                    unsigned* __restrict__ offs,
                                                    int* __restrict__ src_s,
                                                    int* __restrict__ dst_s) {
    const int i = blockIdx.x * 256 + threadIdx.x;
    const int stride = gridDim.x * 256;
    for (int e = i; e < N_EDGES; e += stride) {
        const int d = dst[e];
        const unsigned p = atomicAdd(&offs[d], 1u);
        src_s[p] = src[e];
        dst_s[p] = d;
    }
}

// A = h @ ew1[0:64] + eb1 (bias folded), B = h @ ew1[64:128]; zero scatter bufs.
__global__ __launch_bounds__(256) void node_pre(
    const float* __restrict__ h, const float* __restrict__ ew1,
    const float* __restrict__ eb1,
    float* __restrict__ A, float* __restrict__ B,
    float* __restrict__ h_neigh, float* __restrict__ x_neigh)
{
    __shared__ float wAT[F * NSTR], wBT[F * NSTR];
    const int tid = threadIdx.x;
    for (int idx = tid; idx < F * F; idx += 256) {
        const int k = idx >> 6, n = idx & 63;
        wAT[n * NSTR + k] = ew1[idx];
        wBT[n * NSTR + k] = ew1[F * F + idx];
    }
    __syncthreads();
    const int lane = tid & 63;
    const float e1 = eb1[lane];
    const int nwav = gridDim.x * 4;
    const int wid = blockIdx.x * 4 + (tid >> 6);
    for (int g = wid; g < N_NODES / 8; g += nwav) {
        const int n0 = g * 8;
        float hr[8];
        #pragma unroll
        for (int e = 0; e < 8; ++e) hr[e] = h[(n0 + e) * F + lane];
        float aA[8], aB[8];
        #pragma unroll
        for (int e = 0; e < 8; ++e) { aA[e] = e1; aB[e] = 0.f; }
        #pragma unroll
        for (int kk = 0; kk < 16; ++kk) {
            const f32x4 wa = *(const f32x4*)&wAT[lane * NSTR + kk * 4];
            const f32x4 wb = *(const f32x4*)&wBT[lane * NSTR + kk * 4];
            #pragma unroll
            for (int j = 0; j < 4; ++j) {
                const int k = kk * 4 + j;
                #pragma unroll
                for (int e = 0; e < 8; ++e) {
                    const float hv = bcast(hr[e], k);
                    aA[e] = fmaf(hv, wa[j], aA[e]);
                    aB[e] = fmaf(hv, wb[j], aB[e]);
                }
            }
        }
        #pragma unroll
        for (int e = 0; e < 8; ++e) {
            A[(n0 + e) * F + lane] = aA[e];
            B[(n0 + e) * F + lane] = aB[e];
            h_neigh[(n0 + e) * F + lane] = 0.0f;
        }
        if (lane < 24) x_neigh[n0 * 3 + lane] = 0.0f;
    }
}

// MFMA edge kernel, split-bf16, dst-sorted edges, pipelined gathers.
// A-frag: [m=lane&15][k=quad*8+j] (+32/kb). B-frag: [k=quad*8+j][n=lane&15].
// C/D: col=lane&15 (n), row=quad*4+reg (m=edge).
__global__ __launch_bounds__(256, 3) void edge_mfma(
    const float* __restrict__ A, const float* __restrict__ B,
    const float* __restrict__ x,
    const int* __restrict__ src, const int* __restrict__ dst,
    const float* __restrict__ rw,
    const float* __restrict__ ew2, const float* __restrict__ eb2,
    const float* __restrict__ cw1, const float* __restrict__ cb1,
    const float* __restrict__ cw2,
    float* __restrict__ h_neigh, float* __restrict__ x_neigh)
{
    __shared__ float rwb[F];
    __shared__ unsigned wEp[F * WSTRU];       // packed hi|lo of ew2^T [n][k]
    __shared__ unsigned wCp[F * WSTRU];       // packed hi|lo of cw1^T [n][k]
    __shared__ unsigned mbuf_s[4][16 * MSTR]; // packed hi|lo of m, per wave
    __shared__ float cbuf_s[4][16];
    const int tid = threadIdx.x;
    if (tid < 64) rwb[tid] = rw[tid];
    for (int idx = tid; idx < F * F; idx += 256) {
        const int k = idx >> 6, n = idx & 63;
        const float we = ew2[idx];
        const float wc = cw1[idx];
        const short weh = f2bf(we), wch = f2bf(wc);
        const short wel = f2bf(we - bf2f(weh)), wcl = f2bf(wc - bf2f(wch));
        wEp[n * WSTRU + k] = ((unsigned)(unsigned short)weh << 16) | (unsigned)(unsigned short)wel;
        wCp[n * WSTRU + k] = ((unsigned)(unsigned short)wch << 16) | (unsigned)(unsigned short)wcl;
    }
    __syncthreads();
    const int w = tid >> 6, lane = tid & 63;
    const int col = lane & 15, quad = lane >> 4;
    unsigned* mbuf = &mbuf_s[w][0];
    float* cbuf = &cbuf_s[w][0];

    float eb2c[4], cb1c[4], cw2c[4];
    #pragma unroll
    for (int t = 0; t < 4; ++t) {
        eb2c[t] = eb2[t * 16 + col];
        cb1c[t] = cb1[t * 16 + col];
        cw2c[t] = cw2[t * 16 + col];
    }

    const int eL = lane / 3;                 // coord lanes (<48): edge eL, comp cc
    const int cc = lane - eL * 3;
    const bool cl = lane < 48;
    const int NG = N_EDGES / 16;
    const int nwav = gridDim.x * 4;

    // ---- pipeline preheader: group g0 fully prefetched ----
    const int g0 = blockIdx.x * 4 + w;
    int sv = src[g0 * 16 + col], dv = dst[g0 * 16 + col];
    f32x4 ag[4], bg[4];
    {
        const f32x4* ap = (const f32x4*)(A + (size_t)sv * 64);
        const f32x4* bp = (const f32x4*)(B + (size_t)dv * 64);
        ag[0] = ap[quad * 2];     ag[1] = ap[quad * 2 + 1];
        ag[2] = ap[8 + quad * 2]; ag[3] = ap[8 + quad * 2 + 1];
        bg[0] = bp[quad * 2];     bg[1] = bp[quad * 2 + 1];
        bg[2] = bp[8 + quad * 2]; bg[3] = bp[8 + quad * 2 + 1];
    }
    int md = __shfl(dv, eL, 64);
    float xsr = 0.f, xde = 0.f;
    {
        const int ms = __shfl(sv, eL, 64);
        if (cl) { xsr = x[ms * 3 + cc]; xde = x[md * 3 + cc]; }
    }

    for (int g = g0; g < NG; g += nwav) {
        // issue next group's index loads immediately
        const int gn = g + nwav;
        const int gl = (gn < NG) ? gn : g;
        const int sv2 = src[gl * 16 + col];
        const int dv2 = dst[gl * 16 + col];

        // radial + normalized diff for current group
        const float xs = xsr - xde;
        const float xx = xs * xs;
        const int b3 = col * 3;
        const float radE = __shfl(xx, b3, 64) + __shfl(xx, b3 + 1, 64)
                         + __shfl(xx, b3 + 2, 64);        // radial of edge (col)
        const float rad_e = __shfl(radE, eL, 64);
        const float xdn = xs / (sqrtf(rad_e) + 1e-30f);

        // m1 = silu(A'[src]+B[dst]+rad*rw) -> hi/lo A-frags  (consumes ag/bg)
        short8 m1h[2], m1l[2];
        const float* agf = (const float*)ag;
        const float* bgf = (const float*)bg;
        #pragma unroll
        for (int kb = 0; kb < 2; ++kb) {
            const f32x4 r0 = *(const f32x4*)&rwb[kb * 32 + quad * 8];
            const f32x4 r1 = *(const f32x4*)&rwb[kb * 32 + quad * 8 + 4];
            short8 fh, fl;
            #pragma unroll
            for (int j = 0; j < 8; ++j) {
                const float rwj = (j < 4) ? r0[j] : r1[j - 4];
                const float pre = agf[kb * 8 + j] + bgf[kb * 8 + j] + radE * rwj;
                const float v = silu_f(pre);
                const short hi = f2bf(v);
                fh[j] = hi;
                fl[j] = f2bf(v - bf2f(hi));
            }
            m1h[kb] = fh; m1l[kb] = fl;
        }

        // ag/bg dead -> issue next group's gathers into the same registers
        {
            const f32x4* ap = (const f32x4*)(A + (size_t)sv2 * 64);
            const f32x4* bp = (const f32x4*)(B + (size_t)dv2 * 64);
            ag[0] = ap[quad * 2];     ag[1] = ap[quad * 2 + 1];
            ag[2] = ap[8 + quad * 2]; ag[3] = ap[8 + quad * 2 + 1];
            bg[0] = bp[quad * 2];     bg[1] = bp[quad * 2 + 1];
            bg[2] = bp[8 + quad * 2]; bg[3] = bp[8 + quad * 2 + 1];
        }
        const int md2 = __shfl(dv2, eL, 64);
        float xsr2 = 0.f, xde2 = 0.f;
        {
            const int ms2 = __shfl(sv2, eL, 64);
            if (cl) { xsr2 = x[ms2 * 3 + cc]; xde2 = x[md2 * 3 + cc]; }
        }

        // GEMM1: m_pre = m1 @ ew2   (hi*hi + lo*hi + hi*lo), weights from LDS
        f32x4 acc[4];
        #pragma unroll
        for (int t = 0; t < 4; ++t) {
            f32x4 z = {0.f, 0.f, 0.f, 0.f};
            #pragma unroll
            for (int kb = 0; kb < 2; ++kb) {
                const u32x4* wp = (const u32x4*)&wEp[(t * 16 + col) * WSTRU + kb * 32 + quad * 8];
                short8 wh, wl;
                unpack8(wp[0], wp[1], &wh, &wl);
                z = __builtin_amdgcn_mfma_f32_16x16x32_bf16(m1h[kb], wh, z, 0, 0, 0);
                z = __builtin_amdgcn_mfma_f32_16x16x32_bf16(m1l[kb], wh, z, 0, 0, 0);
                z = __builtin_amdgcn_mfma_f32_16x16x32_bf16(m1h[kb], wl, z, 0, 0, 0);
            }
            acc[t] = z;
        }

        // dst rows this lane's C/D covers (current group)
        int dstr[4];
        #pragma unroll
        for (int r = 0; r < 4; ++r) dstr[r] = __shfl(dv, quad * 4 + r, 64);

        // m = silu(m_pre + eb2): scatter + stash packed hi/lo to LDS
        #pragma unroll
        for (int t = 0; t < 4; ++t)
            #pragma unroll
            for (int r = 0; r < 4; ++r) {
                const float v = silu_f(acc[t][r] + eb2c[t]);
                const short hi = f2bf(v);
                const short lo = f2bf(v - bf2f(hi));
                mbuf[(quad * 4 + r) * MSTR + t * 16 + col] =
                    ((unsigned)(unsigned short)hi << 16) | (unsigned)(unsigned short)lo;
                atomicAdd(&h_neigh[(size_t)dstr[r] * 64 + t * 16 + col], v);
            }

        // m as hi/lo A-frags (LDS round trip = C/D -> A layout transform)
        short8 mh[2], ml[2];
        #pragma unroll
        for (int kb = 0; kb < 2; ++kb) {
            const u32x4* mp = (const u32x4*)&mbuf[col * MSTR + kb * 32 + quad * 8];
            unpack8(mp[0], mp[1], &mh[kb], &ml[kb]);
        }

        // GEMM2: c1_pre = m @ cw1
        f32x4 acc2[4];
        #pragma unroll
        for (int t = 0; t < 4; ++t) {
            f32x4 z = {0.f, 0.f, 0.f, 0.f};
            #pragma unroll
            for (int kb = 0; kb < 2; ++kb) {
                const u32x4* wp = (const u32x4*)&wCp[(t * 16 + col) * WSTRU + kb * 32 + quad * 8];
                short8 wh, wl;
                unpack8(wp[0], wp[1], &wh, &wl);
                z = __builtin_amdgcn_mfma_f32_16x16x32_bf16(mh[kb], wh, z, 0, 0, 0);
                z = __builtin_amdgcn_mfma_f32_16x16x32_bf16(ml[kb], wh, z, 0, 0, 0);
                z = __builtin_amdgcn_mfma_f32_16x16x32_bf16(mh[kb], wl, z, 0, 0, 0);
            }
            acc2[t] = z;
        }

        // c[e] = sum_f silu(c1_pre + cb1)[e][f] * cw2[f]
        float part[4] = {0.f, 0.f, 0.f, 0.f};
        #pragma unroll
        for (int t = 0; t < 4; ++t)
            #pragma unroll
            for (int r = 0; r < 4; ++r)
                part[r] = fmaf(silu_f(acc2[t][r] + cb1c[t]), cw2c[t], part[r]);
        #pragma unroll
        for (int off = 8; off >= 1; off >>= 1)
            #pragma unroll
            for (int r = 0; r < 4; ++r)
                part[r] += __shfl_xor(part[r], off, 64);

        if (col == 0) {
            f32x4 cv = {part[0], part[1], part[2], part[3]};
            *(f32x4*)&cbuf[quad * 4] = cv;
        }
        if (cl)
            atomicAdd(&x_neigh[(size_t)md * 3 + cc], cbuf[eL] * xdn);

        // rotate pipeline state
        sv = sv2; dv = dv2; md = md2; xsr = xsr2; xde = xde2;
    }
}

// h_new = silu([h,h_neigh] @ nw1 + nb1) @ nw2 + nb2;  x_new = x + x_neigh
__global__ __launch_bounds__(256) void node_post(
    const float* __restrict__ h, const float* __restrict__ hng,
    const float* __restrict__ nw1, const float* __restrict__ nb1,
    const float* __restrict__ nw2, const float* __restrict__ nb2,
    const float* __restrict__ x_in, const float* __restrict__ xng,
    float* __restrict__ h_out, float* __restrict__ x_out)
{
    __shared__ float w1aT[F * NSTR], w1bT[F * NSTR], w2T[F * NSTR];
    const int tid = threadIdx.x;
    for (int idx = tid; idx < F * F; idx += 256) {
        const int k = idx >> 6, n = idx & 63;
        w1aT[n * NSTR + k] = nw1[idx];
        w1bT[n * NSTR + k] = nw1[F * F + idx];
        w2T[n * NSTR + k]  = nw2[idx];
    }
    __syncthreads();
    const int lane = tid & 63;
    const float b1 = nb1[lane], b2 = nb2[lane];
    const int nwav = gridDim.x * 4;
    const int wid = blockIdx.x * 4 + (tid >> 6);
    for (int g = wid; g < N_NODES / 8; g += nwav) {
        const int n0 = g * 8;
        float hr[8], gr[8];
        #pragma unroll
        for (int e = 0; e < 8; ++e) {
            hr[e] = h[(n0 + e) * F + lane];
            gr[e] = hng[(n0 + e) * F + lane];
        }
        float t8[8];
        #pragma unroll
        for (int e = 0; e < 8; ++e) t8[e] = b1;
        #pragma unroll
        for (int kk = 0; kk < 16; ++kk) {
            const f32x4 wa = *(const f32x4*)&w1aT[lane * NSTR + kk * 4];
            const f32x4 wb = *(const f32x4*)&w1bT[lane * NSTR + kk * 4];
            #pragma unroll
            for (int j = 0; j < 4; ++j) {
                const int k = kk * 4 + j;
                #pragma unroll
                for (int e = 0; e < 8; ++e) {
                    t8[e] = fmaf(bcast(hr[e], k), wa[j], t8[e]);
                    t8[e] = fmaf(bcast(gr[e], k), wb[j], t8[e]);
                }
            }
        }
        #pragma unroll
        for (int e = 0; e < 8; ++e) t8[e] = silu_f(t8[e]);
        float o[8];
        #pragma unroll
        for (int e = 0; e < 8; ++e) o[e] = b2;
        #pragma unroll
        for (int kk = 0; kk < 16; ++kk) {
            const f32x4 wv = *(const f32x4*)&w2T[lane * NSTR + kk * 4];
            #pragma unroll
            for (int j = 0; j < 4; ++j) {
                const int k = kk * 4 + j;
                #pragma unroll
                for (int e = 0; e < 8; ++e)
                    o[e] = fmaf(bcast(t8[e], k), wv[j], o[e]);
            }
        }
        #pragma unroll
        for (int e = 0; e < 8; ++e) h_out[(n0 + e) * F + lane] = o[e];
        if (lane < 24) x_out[n0 * 3 + lane] = x_in[n0 * 3 + lane] + xng[n0 * 3 + lane];
    }
}

extern "C" void kernel_launch(void* const* d_in, const int* in_sizes, int n_in,
                              void* d_out, int out_size, void* d_ws, size_t ws_size,
                              hipStream_t stream) {
    const float* h_in0 = (const float*)d_in[0];
    const float* x_in0 = (const float*)d_in[1];
    const int*   src   = (const int*)d_in[2];
    const int*   dst   = (const int*)d_in[3];
    const float* ew1   = (const float*)d_in[4];
    const float* eb1   = (const float*)d_in[5];
    const float* ew2   = (const float*)d_in[6];
    const float* eb2   = (const float*)d_in[7];
    const float* nw1   = (const float*)d_in[8];
    const float* nb1   = (const float*)d_in[9];
    const float* nw2   = (const float*)d_in[10];
    const float* nb2   = (const float*)d_in[11];
    const float* cw1   = (const float*)d_in[12];
    const float* cb1   = (const float*)d_in[13];
    const float* cw2   = (const float*)d_in[14];
    float* out = (float*)d_out;

    const size_t NF = (size_t)N_NODES * F;
    float* A   = (float*)d_ws;       // [N,64] (+eb1 folded)
    float* Bm  = A + NF;             // [N,64]
    float* hng = Bm + NF;            // h_neigh [N,64]
    float* h0  = hng + NF;           // h ping  [N,64]
    float* h1  = h0 + NF;            // h pong  [N,64]
    float* xw  = h1 + NF;            // x       [N,3]
    float* xng = xw + (size_t)N_NODES * 3;  // x_neigh [N,3]
    unsigned* counts  = (unsigned*)(xng + (size_t)N_NODES * 3); // [N] -> excl offsets (in place)
    unsigned* partial = counts + N_NODES;                        // [256]
    int* src_s = (int*)(partial + 256);                          // [E] sorted by dst
    int* dst_s = src_s + N_EDGES;                                // [E]

    // ---- counting sort of edges by dst (once; reused by all 4 layers) ----
    sort_zero<<<128, 256, 0, stream>>>(counts);
    sort_hist<<<1024, 256, 0, stream>>>(dst, counts);
    sort_chunk_sums<<<NCHUNK, 512, 0, stream>>>(counts, partial);
    sort_scan_partials<<<1, 256, 0, stream>>>(partial);
    sort_scan_chunks<<<NCHUNK, 512, 0, stream>>>(counts, partial);
    sort_scatter<<<1024, 256, 0, stream>>>(src, dst, counts, src_s, dst_s);

    for (int d = 0; d < 4; ++d) {
        const float* hcur = (d == 0) ? h_in0 : ((d & 1) ? h0 : h1);
        float* hout = (d & 1) ? h1 : h0;
        const float* xcur = (d == 0) ? x_in0 : xw;
        float* xout = (d == 3) ? out : xw;
        node_pre<<<512, 256, 0, stream>>>(hcur, ew1 + (size_t)d * 129 * F,
                                          eb1 + d * F, A, Bm, hng, xng);
        edge_mfma<<<768, 256, 0, stream>>>(A, Bm, xcur, src_s, dst_s,
            ew1 + (size_t)d * 129 * F + 128 * F,
            ew2 + (size_t)d * F * F, eb2 + d * F,
            cw1 + (size_t)d * F * F, cb1 + d * F, cw2 + d * F,
            hng, xng);
        node_post<<<768, 256, 0, stream>>>(hcur, hng,
            nw1 + (size_t)d * 2 * F * F, nb1 + d * F,
            nw2 + (size_t)d * F * F, nb2 + d * F,
            xcur, xng, hout, xout);
    }
}

// Round 6
// 3016.167 us; speedup vs baseline: 2.7024x; 2.7024x over previous
//
#include <hip/hip_runtime.h>

#define N_NODES 100000
#define N_EDGES 1600000
#define F 64
#define NCHUNK 196           // ceil(N_NODES/512)

static_assert(N_NODES % 8 == 0, "node groups exact");
static_assert(N_EDGES % 16 == 0, "edge groups exact");

using short8 = __attribute__((ext_vector_type(8))) short;  // 8 bf16 (4 VGPRs)
using f32x4  = __attribute__((ext_vector_type(4))) float;
using u32x4  = __attribute__((ext_vector_type(4))) unsigned;

#define WSTRU 68  // uint stride for packed weight rows (16B multiple, odd/4)
#define MSTR  68  // uint stride for packed m buffer rows
#define NSTR  68  // float stride for node-kernel transposed weights

__device__ __forceinline__ float silu_f(float v) {
    return v / (1.0f + __expf(-v));
}
__device__ __forceinline__ short f2bf(float f) {          // f32 -> bf16 RNE
    unsigned u = __float_as_uint(f);
    unsigned r = (u + 0x7fffu + ((u >> 16) & 1u)) >> 16;
    return (short)r;
}
__device__ __forceinline__ float bf2f(short s) {
    return __uint_as_float(((unsigned)(unsigned short)s) << 16);
}
__device__ __forceinline__ float bcast(float v, int l) {  // v_readlane
    return __int_as_float(__builtin_amdgcn_readlane(__float_as_int(v), l));
}
// unpack 8 packed (hi<<16|lo) uints into hi/lo short8 via v_perm_b32
__device__ __forceinline__ void unpack8(const u32x4 u0, const u32x4 u1,
                                        short8* hi, short8* lo) {
    union { unsigned d[4]; short8 s; } H, L;
    H.d[0] = __builtin_amdgcn_perm(u0[1], u0[0], 0x07060302u);
    H.d[1] = __builtin_amdgcn_perm(u0[3], u0[2], 0x07060302u);
    H.d[2] = __builtin_amdgcn_perm(u1[1], u1[0], 0x07060302u);
    H.d[3] = __builtin_amdgcn_perm(u1[3], u1[2], 0x07060302u);
    L.d[0] = __builtin_amdgcn_perm(u0[1], u0[0], 0x05040100u);
    L.d[1] = __builtin_amdgcn_perm(u0[3], u0[2], 0x05040100u);
    L.d[2] = __builtin_amdgcn_perm(u1[1], u1[0], 0x05040100u);
    L.d[3] = __builtin_amdgcn_perm(u1[3], u1[2], 0x05040100u);
    *hi = H.s; *lo = L.s;
}

// ---------------- counting sort of edges by dst ----------------
__global__ __launch_bounds__(256) void sort_zero(unsigned* __restrict__ counts) {
    const int i = blockIdx.x * 256 + threadIdx.x;
    const int stride = gridDim.x * 256;
    for (int j = i; j < N_NODES; j += stride) counts[j] = 0u;
}
__global__ __launch_bounds__(256) void sort_hist(const int* __restrict__ dst,
                                                 unsigned* __restrict__ counts) {
    const int i = blockIdx.x * 256 + threadIdx.x;
    const int stride = gridDim.x * 256;
    for (int e = i; e < N_EDGES; e += stride)
        atomicAdd(&counts[dst[e]], 1u);
}
__global__ __launch_bounds__(512) void sort_chunk_sums(const unsigned* __restrict__ counts,
                                                       unsigned* __restrict__ partial) {
    __shared__ unsigned red[512];
    const int t = threadIdx.x;
    const int i = blockIdx.x * 512 + t;
    red[t] = (i < N_NODES) ? counts[i] : 0u;
    __syncthreads();
    for (int off = 256; off >= 1; off >>= 1) {
        if (t < off) red[t] += red[t + off];
        __syncthreads();
    }
    if (t == 0) partial[blockIdx.x] = red[0];
}
__global__ __launch_bounds__(256) void sort_scan_partials(unsigned* __restrict__ partial) {
    __shared__ unsigned tmp[256];
    const int t = threadIdx.x;
    const unsigned v = (t < NCHUNK) ? partial[t] : 0u;
    tmp[t] = v;
    __syncthreads();
    for (int off = 1; off < 256; off <<= 1) {
        const unsigned a = (t >= off) ? tmp[t - off] : 0u;
        __syncthreads();
        tmp[t] += a;
        __syncthreads();
    }
    if (t < NCHUNK) partial[t] = tmp[t] - v;   // exclusive
}
__global__ __launch_bounds__(512) void sort_scan_chunks(unsigned* __restrict__ counts,
                                                        const unsigned* __restrict__ partial) {
    __shared__ unsigned tmp[512];
    const int t = threadIdx.x;
    const int i = blockIdx.x * 512 + t;
    const unsigned v = (i < N_NODES) ? counts[i] : 0u;
    tmp[t] = v;
    __syncthreads();
    for (int off = 1; off < 512; off <<= 1) {
        const unsigned a = (t >= off) ? tmp[t - off] : 0u;
        __syncthreads();
        tmp[t] += a;
        __syncthreads();
    }
    if (i < N_NODES) counts[i] = tmp[t] - v + partial[blockIdx.x];  // exclusive offsets
}
__global__ __launch_bounds__(256) void sort_scatter(const int* __restrict__ src,
                                                    const int* __restrict__ dst,
                                                    unsigned* __restrict__ offs,
                                                    int* __restrict__ src_s,
                                                    int* __restrict__ dst_s) {
    const int i = blockIdx.x * 256 + threadIdx.x;
    const int stride = gridDim.x * 256;
    for (int e = i; e < N_EDGES; e += stride) {
        const int d = dst[e];
        const unsigned p = atomicAdd(&offs[d], 1u);
        src_s[p] = src[e];
        dst_s[p] = d;
    }
}

// A = h @ ew1[0:64] + eb1 (bias folded), B = h @ ew1[64:128]; zero scatter bufs.
__global__ __launch_bounds__(256) void node_pre(
    const float* __restrict__ h, const float* __restrict__ ew1,
    const float* __restrict__ eb1,
    float* __restrict__ A, float* __restrict__ B,
    float* __restrict__ h_neigh, float* __restrict__ x_neigh)
{
    __shared__ float wAT[F * NSTR], wBT[F * NSTR];
    const int tid = threadIdx.x;
    for (int idx = tid; idx < F * F; idx += 256) {
        const int k = idx >> 6, n = idx & 63;
        wAT[n * NSTR + k] = ew1[idx];
        wBT[n * NSTR + k] = ew1[F * F + idx];
    }
    __syncthreads();
    const int lane = tid & 63;
    const float e1 = eb1[lane];
    const int nwav = gridDim.x * 4;
    const int wid = blockIdx.x * 4 + (tid >> 6);
    for (int g = wid; g < N_NODES / 8; g += nwav) {
        const int n0 = g * 8;
        float hr[8];
        #pragma unroll
        for (int e = 0; e < 8; ++e) hr[e] = h[(n0 + e) * F + lane];
        float aA[8], aB[8];
        #pragma unroll
        for (int e = 0; e < 8; ++e) { aA[e] = e1; aB[e] = 0.f; }
        #pragma unroll
        for (int kk = 0; kk < 16; ++kk) {
            const f32x4 wa = *(const f32x4*)&wAT[lane * NSTR + kk * 4];
            const f32x4 wb = *(const f32x4*)&wBT[lane * NSTR + kk * 4];
            #pragma unroll
            for (int j = 0; j < 4; ++j) {
                const int k = kk * 4 + j;
                #pragma unroll
                for (int e = 0; e < 8; ++e) {
                    const float hv = bcast(hr[e], k);
                    aA[e] = fmaf(hv, wa[j], aA[e]);
                    aB[e] = fmaf(hv, wb[j], aB[e]);
                }
            }
        }
        #pragma unroll
        for (int e = 0; e < 8; ++e) {
            A[(n0 + e) * F + lane] = aA[e];
            B[(n0 + e) * F + lane] = aB[e];
            h_neigh[(n0 + e) * F + lane] = 0.0f;
        }
        if (lane < 24) x_neigh[n0 * 3 + lane] = 0.0f;
    }
}

// MFMA edge kernel, split-bf16, dst-sorted edges, SEGMENTED-REDUCED scatter.
// A-frag: [m=lane&15][k=quad*8+j] (+32/kb). B-frag: [k=quad*8+j][n=lane&15].
// C/D: col=lane&15 (n), row=quad*4+reg (m=edge).
__global__ __launch_bounds__(256, 3) void edge_mfma(
    const float* __restrict__ A, const float* __restrict__ B,
    const float* __restrict__ x,
    const int* __restrict__ src, const int* __restrict__ dst,
    const float* __restrict__ rw,
    const float* __restrict__ ew2, const float* __restrict__ eb2,
    const float* __restrict__ cw1, const float* __restrict__ cb1,
    const float* __restrict__ cw2,
    float* __restrict__ h_neigh, float* __restrict__ x_neigh)
{
    __shared__ float rwb[F];
    __shared__ unsigned wEp[F * WSTRU];       // packed hi|lo of ew2^T [n][k]
    __shared__ unsigned wCp[F * WSTRU];       // packed hi|lo of cw1^T [n][k]
    __shared__ unsigned mbuf_s[4][16 * MSTR]; // packed hi|lo of m, per wave
    __shared__ float cbuf_s[4][16];
    const int tid = threadIdx.x;
    if (tid < 64) rwb[tid] = rw[tid];
    for (int idx = tid; idx < F * F; idx += 256) {
        const int k = idx >> 6, n = idx & 63;
        const float we = ew2[idx];
        const float wc = cw1[idx];
        const short weh = f2bf(we), wch = f2bf(wc);
        const short wel = f2bf(we - bf2f(weh)), wcl = f2bf(wc - bf2f(wch));
        wEp[n * WSTRU + k] = ((unsigned)(unsigned short)weh << 16) | (unsigned)(unsigned short)wel;
        wCp[n * WSTRU + k] = ((unsigned)(unsigned short)wch << 16) | (unsigned)(unsigned short)wcl;
    }
    __syncthreads();
    const int w = tid >> 6, lane = tid & 63;
    const int col = lane & 15, quad = lane >> 4;
    unsigned* mbuf = &mbuf_s[w][0];
    float* cbuf = &cbuf_s[w][0];

    float eb2c[4], cb1c[4], cw2c[4];
    #pragma unroll
    for (int t = 0; t < 4; ++t) {
        eb2c[t] = eb2[t * 16 + col];
        cb1c[t] = cb1[t * 16 + col];
        cw2c[t] = cw2[t * 16 + col];
    }

    const int eL = lane / 3;                 // coord lanes (<48): edge eL, comp cc
    const int cc = lane - eL * 3;
    const bool cl = lane < 48;
    const int NG = N_EDGES / 16;
    const int nwav = gridDim.x * 4;

    // ---- pipeline preheader: group g0 fully prefetched ----
    const int g0 = blockIdx.x * 4 + w;
    int sv = src[g0 * 16 + col], dv = dst[g0 * 16 + col];
    f32x4 ag[4], bg[4];
    {
        const f32x4* ap = (const f32x4*)(A + (size_t)sv * 64);
        const f32x4* bp = (const f32x4*)(B + (size_t)dv * 64);
        ag[0] = ap[quad * 2];     ag[1] = ap[quad * 2 + 1];
        ag[2] = ap[8 + quad * 2]; ag[3] = ap[8 + quad * 2 + 1];
        bg[0] = bp[quad * 2];     bg[1] = bp[quad * 2 + 1];
        bg[2] = bp[8 + quad * 2]; bg[3] = bp[8 + quad * 2 + 1];
    }
    int md = __shfl(dv, eL, 64);
    float xsr = 0.f, xde = 0.f;
    {
        const int ms = __shfl(sv, eL, 64);
        if (cl) { xsr = x[ms * 3 + cc]; xde = x[md * 3 + cc]; }
    }

    for (int g = g0; g < NG; g += nwav) {
        // issue next group's index loads immediately
        const int gn = g + nwav;
        const int gl = (gn < NG) ? gn : g;
        const int sv2 = src[gl * 16 + col];
        const int dv2 = dst[gl * 16 + col];

        // radial + normalized diff for current group
        const float xs = xsr - xde;
        const float xx = xs * xs;
        const int b3 = col * 3;
        const float radE = __shfl(xx, b3, 64) + __shfl(xx, b3 + 1, 64)
                         + __shfl(xx, b3 + 2, 64);        // radial of edge (col)
        const float rad_e = __shfl(radE, eL, 64);
        const float xdn = xs / (sqrtf(rad_e) + 1e-30f);

        // wave-uniform dst of all 16 edges (sorted -> runs)
        int dst16[16];
        #pragma unroll
        for (int r = 0; r < 16; ++r)
            dst16[r] = __builtin_amdgcn_readlane(dv, r);
        unsigned bmask = 1u;                  // run-start flags
        #pragma unroll
        for (int r = 1; r < 16; ++r)
            if (dst16[r] != dst16[r - 1]) bmask |= (1u << r);

        // m1 = silu(A'[src]+B[dst]+rad*rw) -> hi/lo A-frags  (consumes ag/bg)
        short8 m1h[2], m1l[2];
        const float* agf = (const float*)ag;
        const float* bgf = (const float*)bg;
        #pragma unroll
        for (int kb = 0; kb < 2; ++kb) {
            const f32x4 r0 = *(const f32x4*)&rwb[kb * 32 + quad * 8];
            const f32x4 r1 = *(const f32x4*)&rwb[kb * 32 + quad * 8 + 4];
            short8 fh, fl;
            #pragma unroll
            for (int j = 0; j < 8; ++j) {
                const float rwj = (j < 4) ? r0[j] : r1[j - 4];
                const float pre = agf[kb * 8 + j] + bgf[kb * 8 + j] + radE * rwj;
                const float v = silu_f(pre);
                const short hi = f2bf(v);
                fh[j] = hi;
                fl[j] = f2bf(v - bf2f(hi));
            }
            m1h[kb] = fh; m1l[kb] = fl;
        }

        // ag/bg dead -> issue next group's gathers into the same registers
        {
            const f32x4* ap = (const f32x4*)(A + (size_t)sv2 * 64);
            const f32x4* bp = (const f32x4*)(B + (size_t)dv2 * 64);
            ag[0] = ap[quad * 2];     ag[1] = ap[quad * 2 + 1];
            ag[2] = ap[8 + quad * 2]; ag[3] = ap[8 + quad * 2 + 1];
            bg[0] = bp[quad * 2];     bg[1] = bp[quad * 2 + 1];
            bg[2] = bp[8 + quad * 2]; bg[3] = bp[8 + quad * 2 + 1];
        }
        const int md2 = __shfl(dv2, eL, 64);
        float xsr2 = 0.f, xde2 = 0.f;
        {
            const int ms2 = __shfl(sv2, eL, 64);
            if (cl) { xsr2 = x[ms2 * 3 + cc]; xde2 = x[md2 * 3 + cc]; }
        }

        // GEMM1: m_pre = m1 @ ew2   (hi*hi + lo*hi + hi*lo), weights from LDS
        f32x4 acc[4];
        #pragma unroll
        for (int t = 0; t < 4; ++t) {
            f32x4 z = {0.f, 0.f, 0.f, 0.f};
            #pragma unroll
            for (int kb = 0; kb < 2; ++kb) {
                const u32x4* wp = (const u32x4*)&wEp[(t * 16 + col) * WSTRU + kb * 32 + quad * 8];
                short8 wh, wl;
                unpack8(wp[0], wp[1], &wh, &wl);
                z = __builtin_amdgcn_mfma_f32_16x16x32_bf16(m1h[kb], wh, z, 0, 0, 0);
                z = __builtin_amdgcn_mfma_f32_16x16x32_bf16(m1l[kb], wh, z, 0, 0, 0);
                z = __builtin_amdgcn_mfma_f32_16x16x32_bf16(m1h[kb], wl, z, 0, 0, 0);
            }
            acc[t] = z;
        }

        // m = silu(m_pre + eb2): stash packed hi/lo to LDS (no atomics here)
        #pragma unroll
        for (int t = 0; t < 4; ++t)
            #pragma unroll
            for (int r = 0; r < 4; ++r) {
                const float v = silu_f(acc[t][r] + eb2c[t]);
                const short hi = f2bf(v);
                const short lo = f2bf(v - bf2f(hi));
                mbuf[(quad * 4 + r) * MSTR + t * 16 + col] =
                    ((unsigned)(unsigned short)hi << 16) | (unsigned)(unsigned short)lo;
            }

        // segmented reduce over sorted runs: lane = feature, rows = 16 edges.
        // dst16[] is uniform -> run boundaries are wave-uniform branches.
        {
            float accf = 0.f;
            #pragma unroll
            for (int r = 0; r < 16; ++r) {
                const unsigned pm = mbuf[r * MSTR + lane];
                accf += bf2f((short)(pm >> 16)) + bf2f((short)(pm & 0xffffu));
                const bool endrun = (r == 15) || (dst16[r + 1] != dst16[r]);
                if (endrun) {
                    atomicAdd(&h_neigh[(size_t)dst16[r] * 64 + lane], accf);
                    accf = 0.f;
                }
            }
        }

        // m as hi/lo A-frags (LDS round trip = C/D -> A layout transform)
        short8 mh[2], ml[2];
        #pragma unroll
        for (int kb = 0; kb < 2; ++kb) {
            const u32x4* mp = (const u32x4*)&mbuf[col * MSTR + kb * 32 + quad * 8];
            unpack8(mp[0], mp[1], &mh[kb], &ml[kb]);
        }

        // GEMM2: c1_pre = m @ cw1
        f32x4 acc2[4];
        #pragma unroll
        for (int t = 0; t < 4; ++t) {
            f32x4 z = {0.f, 0.f, 0.f, 0.f};
            #pragma unroll
            for (int kb = 0; kb < 2; ++kb) {
                const u32x4* wp = (const u32x4*)&wCp[(t * 16 + col) * WSTRU + kb * 32 + quad * 8];
                short8 wh, wl;
                unpack8(wp[0], wp[1], &wh, &wl);
                z = __builtin_amdgcn_mfma_f32_16x16x32_bf16(mh[kb], wh, z, 0, 0, 0);
                z = __builtin_amdgcn_mfma_f32_16x16x32_bf16(ml[kb], wh, z, 0, 0, 0);
                z = __builtin_amdgcn_mfma_f32_16x16x32_bf16(mh[kb], wl, z, 0, 0, 0);
            }
            acc2[t] = z;
        }

        // c[e] = sum_f silu(c1_pre + cb1)[e][f] * cw2[f]
        float part[4] = {0.f, 0.f, 0.f, 0.f};
        #pragma unroll
        for (int t = 0; t < 4; ++t)
            #pragma unroll
            for (int r = 0; r < 4; ++r)
                part[r] = fmaf(silu_f(acc2[t][r] + cb1c[t]), cw2c[t], part[r]);
        #pragma unroll
        for (int off = 8; off >= 1; off >>= 1)
            #pragma unroll
            for (int r = 0; r < 4; ++r)
                part[r] += __shfl_xor(part[r], off, 64);

        if (col == 0) {
            f32x4 cv = {part[0], part[1], part[2], part[3]};
            *(f32x4*)&cbuf[quad * 4] = cv;
        }

        // x_neigh: segmented shuffle-scan over edges, atomic only at run ends.
        {
            const float ct = cbuf[eL] * xdn;       // per (edge,comp), lanes<48
            // run start of my edge: highest set bit of bmask at or below eL
            const unsigned mlow = bmask & ((2u << eL) - 1u);
            const int rs = 31 - __clz(mlow);       // mlow != 0 (bit0 set)
            float v = ct;
            #pragma unroll
            for (int off = 1; off <= 8; off <<= 1) {
                int sl = lane - 3 * off;
                sl = (sl < 0) ? lane : sl;
                const float pv = __shfl(v, sl, 64);
                if (eL - off >= rs) v += pv;
            }
            const bool rend = (eL == 15) || ((bmask >> (eL + 1)) & 1u);
            if (cl && rend)
                atomicAdd(&x_neigh[(size_t)dst16[eL] * 3 + cc], v);
        }

        // rotate pipeline state
        sv = sv2; dv = dv2; md = md2; xsr = xsr2; xde = xde2;
    }
}

// h_new = silu([h,h_neigh] @ nw1 + nb1) @ nw2 + nb2;  x_new = x + x_neigh
__global__ __launch_bounds__(256) void node_post(
    const float* __restrict__ h, const float* __restrict__ hng,
    const float* __restrict__ nw1, const float* __restrict__ nb1,
    const float* __restrict__ nw2, const float* __restrict__ nb2,
    const float* __restrict__ x_in, const float* __restrict__ xng,
    float* __restrict__ h_out, float* __restrict__ x_out)
{
    __shared__ float w1aT[F * NSTR], w1bT[F * NSTR], w2T[F * NSTR];
    const int tid = threadIdx.x;
    for (int idx = tid; idx < F * F; idx += 256) {
        const int k = idx >> 6, n = idx & 63;
        w1aT[n * NSTR + k] = nw1[idx];
        w1bT[n * NSTR + k] = nw1[F * F + idx];
        w2T[n * NSTR + k]  = nw2[idx];
    }
    __syncthreads();
    const int lane = tid & 63;
    const float b1 = nb1[lane], b2 = nb2[lane];
    const int nwav = gridDim.x * 4;
    const int wid = blockIdx.x * 4 + (tid >> 6);
    for (int g = wid; g < N_NODES / 8; g += nwav) {
        const int n0 = g * 8;
        float hr[8], gr[8];
        #pragma unroll
        for (int e = 0; e < 8; ++e) {
            hr[e] = h[(n0 + e) * F + lane];
            gr[e] = hng[(n0 + e) * F + lane];
        }
        float t8[8];
        #pragma unroll
        for (int e = 0; e < 8; ++e) t8[e] = b1;
        #pragma unroll
        for (int kk = 0; kk < 16; ++kk) {
            const f32x4 wa = *(const f32x4*)&w1aT[lane * NSTR + kk * 4];
            const f32x4 wb = *(const f32x4*)&w1bT[lane * NSTR + kk * 4];
            #pragma unroll
            for (int j = 0; j < 4; ++j) {
                const int k = kk * 4 + j;
                #pragma unroll
                for (int e = 0; e < 8; ++e) {
                    t8[e] = fmaf(bcast(hr[e], k), wa[j], t8[e]);
                    t8[e] = fmaf(bcast(gr[e], k), wb[j], t8[e]);
                }
            }
        }
        #pragma unroll
        for (int e = 0; e < 8; ++e) t8[e] = silu_f(t8[e]);
        float o[8];
        #pragma unroll
        for (int e = 0; e < 8; ++e) o[e] = b2;
        #pragma unroll
        for (int kk = 0; kk < 16; ++kk) {
            const f32x4 wv = *(const f32x4*)&w2T[lane * NSTR + kk * 4];
            #pragma unroll
            for (int j = 0; j < 4; ++j) {
                const int k = kk * 4 + j;
                #pragma unroll
                for (int e = 0; e < 8; ++e)
                    o[e] = fmaf(bcast(t8[e], k), wv[j], o[e]);
            }
        }
        #pragma unroll
        for (int e = 0; e < 8; ++e) h_out[(n0 + e) * F + lane] = o[e];
        if (lane < 24) x_out[n0 * 3 + lane] = x_in[n0 * 3 + lane] + xng[n0 * 3 + lane];
    }
}

extern "C" void kernel_launch(void* const* d_in, const int* in_sizes, int n_in,
                              void* d_out, int out_size, void* d_ws, size_t ws_size,
                              hipStream_t stream) {
    const float* h_in0 = (const float*)d_in[0];
    const float* x_in0 = (const float*)d_in[1];
    const int*   src   = (const int*)d_in[2];
    const int*   dst   = (const int*)d_in[3];
    const float* ew1   = (const float*)d_in[4];
    const float* eb1   = (const float*)d_in[5];
    const float* ew2   = (const float*)d_in[6];
    const float* eb2   = (const float*)d_in[7];
    const float* nw1   = (const float*)d_in[8];
    const float* nb1   = (const float*)d_in[9];
    const float* nw2   = (const float*)d_in[10];
    const float* nb2   = (const float*)d_in[11];
    const float* cw1   = (const float*)d_in[12];
    const float* cb1   = (const float*)d_in[13];
    const float* cw2   = (const float*)d_in[14];
    float* out = (float*)d_out;

    const size_t NF = (size_t)N_NODES * F;
    float* A   = (float*)d_ws;       // [N,64] (+eb1 folded)
    float* Bm  = A + NF;             // [N,64]
    float* hng = Bm + NF;            // h_neigh [N,64]
    float* h0  = hng + NF;           // h ping  [N,64]
    float* h1  = h0 + NF;            // h pong  [N,64]
    float* xw  = h1 + NF;            // x       [N,3]
    float* xng = xw + (size_t)N_NODES * 3;  // x_neigh [N,3]
    unsigned* counts  = (unsigned*)(xng + (size_t)N_NODES * 3); // [N] -> excl offsets (in place)
    unsigned* partial = counts + N_NODES;                        // [256]
    int* src_s = (int*)(partial + 256);                          // [E] sorted by dst
    int* dst_s = src_s + N_EDGES;                                // [E]

    // ---- counting sort of edges by dst (once; reused by all 4 layers) ----
    sort_zero<<<128, 256, 0, stream>>>(counts);
    sort_hist<<<1024, 256, 0, stream>>>(dst, counts);
    sort_chunk_sums<<<NCHUNK, 512, 0, stream>>>(counts, partial);
    sort_scan_partials<<<1, 256, 0, stream>>>(partial);
    sort_scan_chunks<<<NCHUNK, 512, 0, stream>>>(counts, partial);
    sort_scatter<<<1024, 256, 0, stream>>>(src, dst, counts, src_s, dst_s);

    for (int d = 0; d < 4; ++d) {
        const float* hcur = (d == 0) ? h_in0 : ((d & 1) ? h0 : h1);
        float* hout = (d & 1) ? h1 : h0;
        const float* xcur = (d == 0) ? x_in0 : xw;
        float* xout = (d == 3) ? out : xw;
        node_pre<<<512, 256, 0, stream>>>(hcur, ew1 + (size_t)d * 129 * F,
                                          eb1 + d * F, A, Bm, hng, xng);
        edge_mfma<<<768, 256, 0, stream>>>(A, Bm, xcur, src_s, dst_s,
            ew1 + (size_t)d * 129 * F + 128 * F,
            ew2 + (size_t)d * F * F, eb2 + d * F,
            cw1 + (size_t)d * F * F, cb1 + d * F, cw2 + d * F,
            hng, xng);
        node_post<<<768, 256, 0, stream>>>(hcur, hng,
            nw1 + (size_t)d * 2 * F * F, nb1 + d * F,
            nw2 + (size_t)d * F * F, nb2 + d * F,
            xcur, xng, hout, xout);
    }
}